// Round 1
// baseline (1168.801 us; speedup 1.0000x reference)
//
#include <hip/hip_runtime.h>
#include <math.h>

// Problem dims (fixed by reference)
#define B_ROWS 8192
#define D_IN   256
#define H1_DIM 512
#define H2_DIM 256
#define D_OUT  64
#define EPSF   1e-12f
#define THRESH 0.9f

// ---------------- GEMM: C[M,N] = act(A[M,K] @ W[N,K]^T + b) ----------------
#define TM 128
#define TN 64
#define TK 16
#define LDA (TM + 4)
#define LDW (TN + 4)

template<bool TANH>
__global__ __launch_bounds__(256)
void gemm_bias_act(const float* __restrict__ A, const float* __restrict__ W,
                   const float* __restrict__ bias, float* __restrict__ C,
                   int K, int N) {
  __shared__ float As[TK][LDA];
  __shared__ float Ws[TK][LDW];
  const int tid = threadIdx.x;
  const int bm = blockIdx.x * TM;
  const int bn = blockIdx.y * TN;
  const int tm = (tid >> 4) << 3;   // 0..120 step 8
  const int tn = (tid & 15) << 2;   // 0..60 step 4
  const int lr = tid >> 2;          // 0..63
  const int lc = (tid & 3) << 2;    // 0,4,8,12

  float acc[8][4] = {};

  const float* Aptr0 = A + (size_t)(bm + lr) * K + lc;
  const float* Aptr1 = A + (size_t)(bm + lr + 64) * K + lc;
  const float* Wptr  = W + (size_t)(bn + lr) * K + lc;

  for (int k0 = 0; k0 < K; k0 += TK) {
    float4 a0 = *(const float4*)(Aptr0 + k0);
    float4 a1 = *(const float4*)(Aptr1 + k0);
    float4 w0 = *(const float4*)(Wptr + k0);
    __syncthreads();
    As[lc + 0][lr] = a0.x; As[lc + 1][lr] = a0.y;
    As[lc + 2][lr] = a0.z; As[lc + 3][lr] = a0.w;
    As[lc + 0][lr + 64] = a1.x; As[lc + 1][lr + 64] = a1.y;
    As[lc + 2][lr + 64] = a1.z; As[lc + 3][lr + 64] = a1.w;
    Ws[lc + 0][lr] = w0.x; Ws[lc + 1][lr] = w0.y;
    Ws[lc + 2][lr] = w0.z; Ws[lc + 3][lr] = w0.w;
    __syncthreads();
#pragma unroll
    for (int k = 0; k < TK; ++k) {
      float4 av0 = *(const float4*)&As[k][tm];
      float4 av1 = *(const float4*)&As[k][tm + 4];
      float4 wv  = *(const float4*)&Ws[k][tn];
      float a[8] = {av0.x, av0.y, av0.z, av0.w, av1.x, av1.y, av1.z, av1.w};
      float w[4] = {wv.x, wv.y, wv.z, wv.w};
#pragma unroll
      for (int r = 0; r < 8; ++r)
#pragma unroll
        for (int c = 0; c < 4; ++c)
          acc[r][c] = fmaf(a[r], w[c], acc[r][c]);
    }
  }

  float4 bv = *(const float4*)(bias + bn + tn);
#pragma unroll
  for (int r = 0; r < 8; ++r) {
    float4 v;
    v.x = acc[r][0] + bv.x;
    v.y = acc[r][1] + bv.y;
    v.z = acc[r][2] + bv.z;
    v.w = acc[r][3] + bv.w;
    if (TANH) {
      v.x = tanhf(v.x); v.y = tanhf(v.y); v.z = tanhf(v.z); v.w = tanhf(v.w);
    }
    *(float4*)(C + (size_t)(bm + tm + r) * N + bn + tn) = v;
  }
}

// ---------------- row L2 norms of out[8192,64] ----------------
__global__ __launch_bounds__(256)
void row_norms(const float* __restrict__ out, float* __restrict__ norms) {
  const int wave = threadIdx.x >> 6;
  const int lane = threadIdx.x & 63;
  const int row = blockIdx.x * 4 + wave;
  float v = out[(size_t)row * D_OUT + lane];
  float s = v * v;
#pragma unroll
  for (int m = 32; m; m >>= 1) s += __shfl_xor(s, m, 64);
  if (lane == 0) norms[row] = sqrtf(s);
}

// ---------------- zero d_out ----------------
__global__ __launch_bounds__(256)
void zero_out(float4* __restrict__ res) {
  res[blockIdx.x * 256 + threadIdx.x] = make_float4(0.f, 0.f, 0.f, 0.f);
}

// ---------------- fused pairwise fidelity-threshold + accumulate ----------------
// res[i] = sum_{j != i, fid_ij >= 0.9} out[j]
// fid_ij >= 0.9  <=>  g^2 >= 0.9*(ni+eps)^2*(nj+eps)^2,  g = out_i . out_j
#define NSPLIT 32
#define JCHUNK (B_ROWS / NSPLIT)   // 256

__global__ __launch_bounds__(256)
void pairwise_accum(const float* __restrict__ out, const float* __restrict__ norms,
                    float* __restrict__ res) {
  const int i = blockIdx.x * 256 + threadIdx.x;
  float oi[64];
#pragma unroll
  for (int k = 0; k < 64; ++k) oi[k] = out[(size_t)i * D_OUT + k];
  const float ti = norms[i] + EPSF;
  const float ci = THRESH * (ti * ti);

  float acc[64] = {};
  const int j0 = blockIdx.y * JCHUNK;

  for (int j = j0; j < j0 + JCHUNK; ++j) {
    // j is wave-uniform -> these should become scalar (s_load) fetches
    const float* __restrict__ oj = out + (size_t)j * D_OUT;
    float g0 = 0.f, g1 = 0.f, g2 = 0.f, g3 = 0.f;
#pragma unroll
    for (int k = 0; k < 64; k += 4) {
      g0 = fmaf(oi[k + 0], oj[k + 0], g0);
      g1 = fmaf(oi[k + 1], oj[k + 1], g1);
      g2 = fmaf(oi[k + 2], oj[k + 2], g2);
      g3 = fmaf(oi[k + 3], oj[k + 3], g3);
    }
    const float g = (g0 + g1) + (g2 + g3);
    const float tj = norms[j] + EPSF;
    const bool pass = (g * g >= ci * (tj * tj)) && (j != i);
    if (pass) {
#pragma unroll
      for (int k = 0; k < 64; ++k) acc[k] += oj[k];
    }
  }

#pragma unroll
  for (int k = 0; k < 64; ++k)
    atomicAdd(&res[(size_t)i * D_OUT + k], acc[k]);
}

// ---------------- launch ----------------
extern "C" void kernel_launch(void* const* d_in, const int* in_sizes, int n_in,
                              void* d_out, int out_size, void* d_ws, size_t ws_size,
                              hipStream_t stream) {
  const float* x  = (const float*)d_in[0];
  const float* W1 = (const float*)d_in[1];
  const float* b1 = (const float*)d_in[2];
  const float* W2 = (const float*)d_in[3];
  const float* b2 = (const float*)d_in[4];
  const float* W3 = (const float*)d_in[5];
  const float* b3 = (const float*)d_in[6];
  float* res = (float*)d_out;

  char* ws = (char*)d_ws;
  float* h1    = (float*)ws;                                   // 8192*512 f32 = 16 MB
  float* h2    = (float*)(ws + (size_t)B_ROWS * H1_DIM * 4);   //  8 MB
  float* out   = (float*)(ws + (size_t)B_ROWS * (H1_DIM + H2_DIM) * 4); // 2 MB
  float* norms = (float*)((char*)out + (size_t)B_ROWS * D_OUT * 4);

  gemm_bias_act<true ><<<dim3(64, 8), 256, 0, stream>>>(x,  W1, b1, h1, D_IN,   H1_DIM);
  gemm_bias_act<true ><<<dim3(64, 4), 256, 0, stream>>>(h1, W2, b2, h2, H1_DIM, H2_DIM);
  gemm_bias_act<false><<<dim3(64, 1), 256, 0, stream>>>(h2, W3, b3, out, H2_DIM, D_OUT);
  row_norms<<<B_ROWS / 4, 256, 0, stream>>>(out, norms);
  zero_out<<<(B_ROWS * D_OUT) / 1024, 256, 0, stream>>>((float4*)res);
  pairwise_accum<<<dim3(B_ROWS / 256, NSPLIT), 256, 0, stream>>>(out, norms, res);
}

// Round 2
// 297.693 us; speedup vs baseline: 3.9262x; 3.9262x over previous
//
#include <hip/hip_runtime.h>
#include <math.h>

// Problem dims (fixed by reference)
#define B_ROWS 8192
#define D_IN   256
#define H1_DIM 512
#define H2_DIM 256
#define D_OUT  64
#define EPSF   1e-12f
#define THRESH 0.9f

// ---------------- GEMM: C[M,N] = act(A[M,K] @ W[N,K]^T + b) ----------------
#define TM 128
#define TN 64
#define TK 16
#define LDA (TM + 4)
#define LDW (TN + 4)

template<bool TANH>
__global__ __launch_bounds__(256)
void gemm_bias_act(const float* __restrict__ A, const float* __restrict__ W,
                   const float* __restrict__ bias, float* __restrict__ C,
                   int K, int N) {
  __shared__ float As[TK][LDA];
  __shared__ float Ws[TK][LDW];
  const int tid = threadIdx.x;
  const int bm = blockIdx.x * TM;
  const int bn = blockIdx.y * TN;
  const int tm = (tid >> 4) << 3;   // 0..120 step 8
  const int tn = (tid & 15) << 2;   // 0..60 step 4
  const int lr = tid >> 2;          // 0..63
  const int lc = (tid & 3) << 2;    // 0,4,8,12

  float acc[8][4] = {};

  const float* Aptr0 = A + (size_t)(bm + lr) * K + lc;
  const float* Aptr1 = A + (size_t)(bm + lr + 64) * K + lc;
  const float* Wptr  = W + (size_t)(bn + lr) * K + lc;

  for (int k0 = 0; k0 < K; k0 += TK) {
    float4 a0 = *(const float4*)(Aptr0 + k0);
    float4 a1 = *(const float4*)(Aptr1 + k0);
    float4 w0 = *(const float4*)(Wptr + k0);
    __syncthreads();
    As[lc + 0][lr] = a0.x; As[lc + 1][lr] = a0.y;
    As[lc + 2][lr] = a0.z; As[lc + 3][lr] = a0.w;
    As[lc + 0][lr + 64] = a1.x; As[lc + 1][lr + 64] = a1.y;
    As[lc + 2][lr + 64] = a1.z; As[lc + 3][lr + 64] = a1.w;
    Ws[lc + 0][lr] = w0.x; Ws[lc + 1][lr] = w0.y;
    Ws[lc + 2][lr] = w0.z; Ws[lc + 3][lr] = w0.w;
    __syncthreads();
#pragma unroll
    for (int k = 0; k < TK; ++k) {
      float4 av0 = *(const float4*)&As[k][tm];
      float4 av1 = *(const float4*)&As[k][tm + 4];
      float4 wv  = *(const float4*)&Ws[k][tn];
      float a[8] = {av0.x, av0.y, av0.z, av0.w, av1.x, av1.y, av1.z, av1.w};
      float w[4] = {wv.x, wv.y, wv.z, wv.w};
#pragma unroll
      for (int r = 0; r < 8; ++r)
#pragma unroll
        for (int c = 0; c < 4; ++c)
          acc[r][c] = fmaf(a[r], w[c], acc[r][c]);
    }
  }

  float4 bv = *(const float4*)(bias + bn + tn);
#pragma unroll
  for (int r = 0; r < 8; ++r) {
    float4 v;
    v.x = acc[r][0] + bv.x;
    v.y = acc[r][1] + bv.y;
    v.z = acc[r][2] + bv.z;
    v.w = acc[r][3] + bv.w;
    if (TANH) {
      v.x = tanhf(v.x); v.y = tanhf(v.y); v.z = tanhf(v.z); v.w = tanhf(v.w);
    }
    *(float4*)(C + (size_t)(bm + tm + r) * N + bn + tn) = v;
  }
}

// ---------------- normalize rows: v = out / (||out|| + eps) ----------------
__global__ __launch_bounds__(256)
void normalize_rows(const float* __restrict__ out, float* __restrict__ v) {
  const int wave = threadIdx.x >> 6;
  const int lane = threadIdx.x & 63;
  const int row = blockIdx.x * 4 + wave;
  float val = out[(size_t)row * D_OUT + lane];
  float s = val * val;
#pragma unroll
  for (int m = 32; m; m >>= 1) s += __shfl_xor(s, m, 64);
  v[(size_t)row * D_OUT + lane] = val / (sqrtf(s) + EPSF);
}

// ---------------- zero d_out ----------------
__global__ __launch_bounds__(256)
void zero_out(float4* __restrict__ res) {
  res[blockIdx.x * 256 + threadIdx.x] = make_float4(0.f, 0.f, 0.f, 0.f);
}

// ---------------- fused pairwise Gram + threshold + sparse accumulate ----------------
// res[i] = sum_{j != i, (v_i.v_j)^2 >= 0.9} out[j]
#define TI 128
#define TJ 128
#define LDT (TI + 4)              // 132-float row stride, k-major tiles
#define JSPLIT 16
#define JRANGE (B_ROWS / JSPLIT)  // 512

__global__ __launch_bounds__(256)
void pairwise_accum(const float* __restrict__ v, const float* __restrict__ out,
                    float* __restrict__ res) {
  __shared__ float vi_s[D_OUT][LDT];   // 33 KB
  __shared__ float vj_s[D_OUT][LDT];   // 33 KB
  const int tid = threadIdx.x;
  const int i0 = blockIdx.x * TI;
  const int jbase = blockIdx.y * JRANGE;

  // stage i-tile (128 rows x 64 k), transpose to k-major; coalesced float4 loads
#pragma unroll
  for (int q = 0; q < 8; ++q) {
    const int f = q * 256 + tid;           // float4 index in 128x64 tile
    const int row = f >> 4;
    const int k = (f & 15) << 2;
    float4 d = *(const float4*)(v + (size_t)(i0 + row) * D_OUT + k);
    vi_s[k + 0][row] = d.x; vi_s[k + 1][row] = d.y;
    vi_s[k + 2][row] = d.z; vi_s[k + 3][row] = d.w;
  }

  const int ti = (tid & 15) << 3;   // 0..120 step 8
  const int tj = (tid >> 4) << 3;   // 0..120 step 8

  for (int jc = 0; jc < JRANGE; jc += TJ) {
    const int j0 = jbase + jc;
    __syncthreads();   // previous compute done before restaging vj
#pragma unroll
    for (int q = 0; q < 8; ++q) {
      const int f = q * 256 + tid;
      const int row = f >> 4;
      const int k = (f & 15) << 2;
      float4 d = *(const float4*)(v + (size_t)(j0 + row) * D_OUT + k);
      vj_s[k + 0][row] = d.x; vj_s[k + 1][row] = d.y;
      vj_s[k + 2][row] = d.z; vj_s[k + 3][row] = d.w;
    }
    __syncthreads();

    float g[8][8] = {};
#pragma unroll 8
    for (int k = 0; k < D_OUT; ++k) {
      float4 a0 = *(const float4*)&vi_s[k][ti];
      float4 a1 = *(const float4*)&vi_s[k][ti + 4];
      float4 b0 = *(const float4*)&vj_s[k][tj];
      float4 b1 = *(const float4*)&vj_s[k][tj + 4];
      float a[8] = {a0.x, a0.y, a0.z, a0.w, a1.x, a1.y, a1.z, a1.w};
      float b[8] = {b0.x, b0.y, b0.z, b0.w, b1.x, b1.y, b1.z, b1.w};
#pragma unroll
      for (int r = 0; r < 8; ++r)
#pragma unroll
        for (int c = 0; c < 8; ++c)
          g[r][c] = fmaf(a[r], b[c], g[r][c]);
    }

    // threshold; accumulation is the rare path (adjacency is sparse/empty)
#pragma unroll
    for (int r = 0; r < 8; ++r) {
#pragma unroll
      for (int c = 0; c < 8; ++c) {
        const float gg = g[r][c];
        if (gg * gg >= THRESH) {
          const int i = i0 + ti + r;
          const int j = j0 + tj + c;
          if (i != j) {
            const float* __restrict__ oj = out + (size_t)j * D_OUT;
            float* __restrict__ ri = res + (size_t)i * D_OUT;
            for (int k = 0; k < D_OUT; ++k) atomicAdd(&ri[k], oj[k]);
          }
        }
      }
    }
  }
}

// ---------------- launch ----------------
extern "C" void kernel_launch(void* const* d_in, const int* in_sizes, int n_in,
                              void* d_out, int out_size, void* d_ws, size_t ws_size,
                              hipStream_t stream) {
  const float* x  = (const float*)d_in[0];
  const float* W1 = (const float*)d_in[1];
  const float* b1 = (const float*)d_in[2];
  const float* W2 = (const float*)d_in[3];
  const float* b2 = (const float*)d_in[4];
  const float* W3 = (const float*)d_in[5];
  const float* b3 = (const float*)d_in[6];
  float* res = (float*)d_out;

  char* ws = (char*)d_ws;
  float* h1  = (float*)ws;                                         // 16 MB
  float* h2  = (float*)(ws + (size_t)B_ROWS * H1_DIM * 4);         //  8 MB
  float* out = (float*)(ws + (size_t)B_ROWS * (H1_DIM + H2_DIM) * 4); // 2 MB
  float* v   = h1;   // reuse h1 space; h1 is dead after GEMM2

  gemm_bias_act<true ><<<dim3(64, 8), 256, 0, stream>>>(x,  W1, b1, h1, D_IN,   H1_DIM);
  gemm_bias_act<true ><<<dim3(64, 4), 256, 0, stream>>>(h1, W2, b2, h2, H1_DIM, H2_DIM);
  gemm_bias_act<false><<<dim3(64, 1), 256, 0, stream>>>(h2, W3, b3, out, H2_DIM, D_OUT);
  normalize_rows<<<B_ROWS / 4, 256, 0, stream>>>(out, v);
  zero_out<<<(B_ROWS * D_OUT) / 1024, 256, 0, stream>>>((float4*)res);
  pairwise_accum<<<dim3(B_ROWS / TI, JSPLIT), 256, 0, stream>>>(v, out, res);
}

// Round 3
// 218.688 us; speedup vs baseline: 5.3446x; 1.3613x over previous
//
#include <hip/hip_runtime.h>
#include <hip/hip_bf16.h>
#include <math.h>

// Problem dims (fixed by reference)
#define B_ROWS 8192
#define D_IN   256
#define H1_DIM 512
#define H2_DIM 256
#define D_OUT  64
#define EPSF   1e-12f
#define THRESH 0.9f

typedef __attribute__((ext_vector_type(8))) short short8;   // 8 bf16 = 4 VGPR
typedef __attribute__((ext_vector_type(4))) float f32x4;

// ---------------- GEMM: C[M,N] = act(A[M,K] @ W[N,K]^T + b) ----------------
#define TM 128
#define TN 64
#define TK 16
#define LDA (TM + 4)
#define LDW (TN + 4)

template<bool TANH>
__global__ __launch_bounds__(256)
void gemm_bias_act(const float* __restrict__ A, const float* __restrict__ W,
                   const float* __restrict__ bias, float* __restrict__ C,
                   int K, int N) {
  __shared__ float As[TK][LDA];
  __shared__ float Ws[TK][LDW];
  const int tid = threadIdx.x;
  const int bm = blockIdx.x * TM;
  const int bn = blockIdx.y * TN;
  const int tm = (tid >> 4) << 3;
  const int tn = (tid & 15) << 2;
  const int lr = tid >> 2;
  const int lc = (tid & 3) << 2;

  float acc[8][4] = {};

  const float* Aptr0 = A + (size_t)(bm + lr) * K + lc;
  const float* Aptr1 = A + (size_t)(bm + lr + 64) * K + lc;
  const float* Wptr  = W + (size_t)(bn + lr) * K + lc;

  for (int k0 = 0; k0 < K; k0 += TK) {
    float4 a0 = *(const float4*)(Aptr0 + k0);
    float4 a1 = *(const float4*)(Aptr1 + k0);
    float4 w0 = *(const float4*)(Wptr + k0);
    __syncthreads();
    As[lc + 0][lr] = a0.x; As[lc + 1][lr] = a0.y;
    As[lc + 2][lr] = a0.z; As[lc + 3][lr] = a0.w;
    As[lc + 0][lr + 64] = a1.x; As[lc + 1][lr + 64] = a1.y;
    As[lc + 2][lr + 64] = a1.z; As[lc + 3][lr + 64] = a1.w;
    Ws[lc + 0][lr] = w0.x; Ws[lc + 1][lr] = w0.y;
    Ws[lc + 2][lr] = w0.z; Ws[lc + 3][lr] = w0.w;
    __syncthreads();
#pragma unroll
    for (int k = 0; k < TK; ++k) {
      float4 av0 = *(const float4*)&As[k][tm];
      float4 av1 = *(const float4*)&As[k][tm + 4];
      float4 wv  = *(const float4*)&Ws[k][tn];
      float a[8] = {av0.x, av0.y, av0.z, av0.w, av1.x, av1.y, av1.z, av1.w};
      float w[4] = {wv.x, wv.y, wv.z, wv.w};
#pragma unroll
      for (int r = 0; r < 8; ++r)
#pragma unroll
        for (int c = 0; c < 4; ++c)
          acc[r][c] = fmaf(a[r], w[c], acc[r][c]);
    }
  }

  float4 bv = *(const float4*)(bias + bn + tn);
#pragma unroll
  for (int r = 0; r < 8; ++r) {
    float4 v;
    v.x = acc[r][0] + bv.x;
    v.y = acc[r][1] + bv.y;
    v.z = acc[r][2] + bv.z;
    v.w = acc[r][3] + bv.w;
    if (TANH) {
      v.x = tanhf(v.x); v.y = tanhf(v.y); v.z = tanhf(v.z); v.w = tanhf(v.w);
    }
    *(float4*)(C + (size_t)(bm + tm + r) * N + bn + tn) = v;
  }
}

// ---------------- row norms ----------------
__global__ __launch_bounds__(256)
void row_norms(const float* __restrict__ out, float* __restrict__ norms) {
  const int wave = threadIdx.x >> 6;
  const int lane = threadIdx.x & 63;
  const int row = blockIdx.x * 4 + wave;
  float v = out[(size_t)row * D_OUT + lane];
  float s = v * v;
#pragma unroll
  for (int m = 32; m; m >>= 1) s += __shfl_xor(s, m, 64);
  if (lane == 0) norms[row] = sqrtf(s);
}

// ---------------- pack normalized rows into MFMA-fragment-major bf16 hi/mid ----------------
// frag element: lane l, kstep q, elem e  ->  v[J*16 + (l&15)][q*32 + (l>>4)*8 + e]
// flat index = ((J*128 + q*64 + lane)*8 + e)  == global thread id t * 8 + e
__global__ __launch_bounds__(256)
void pack_split(const float* __restrict__ out, const float* __restrict__ norms,
                short* __restrict__ vph, short* __restrict__ vpm) {
  const int t = blockIdx.x * 256 + threadIdx.x;   // 65536 threads
  const int lane = t & 63;
  const int q = (t >> 6) & 1;
  const int J = t >> 7;
  const int row = J * 16 + (lane & 15);
  const int k0 = q * 32 + ((lane >> 4) << 3);
  const float inv = 1.0f / (norms[row] + EPSF);
  float4 a = *(const float4*)(out + (size_t)row * D_OUT + k0);
  float4 b = *(const float4*)(out + (size_t)row * D_OUT + k0 + 4);
  float vals[8] = {a.x, a.y, a.z, a.w, b.x, b.y, b.z, b.w};
  short h8[8], m8[8];
#pragma unroll
  for (int e = 0; e < 8; ++e) {
    float x = vals[e] * inv;
    __hip_bfloat16 h = __float2bfloat16(x);
    float hf = __bfloat162float(h);
    __hip_bfloat16 m = __float2bfloat16(x - hf);
    h8[e] = *(short*)&h;
    m8[e] = *(short*)&m;
  }
  *(short8*)(vph + (size_t)t * 8) = *(short8*)h8;
  *(short8*)(vpm + (size_t)t * 8) = *(short8*)m8;
}

// ---------------- zero d_out ----------------
__global__ __launch_bounds__(256)
void zero_out(float4* __restrict__ res) {
  res[blockIdx.x * 256 + threadIdx.x] = make_float4(0.f, 0.f, 0.f, 0.f);
}

// ---------------- MFMA Gram + threshold + sparse accumulate ----------------
// res[i] = sum_{j != i, (v_i.v_j)^2 >= 0.9} out[j]
// v_i.v_j computed as bf16x2-split: g = hh + hm + mh   (|err| ~ 2e-5)
#define JSPLIT 8
#define CT 8            // j-tiles per LDS chunk (8 tiles = 128 j-rows)

__global__ __launch_bounds__(256)
void gram_accum(const short* __restrict__ vph, const short* __restrict__ vpm,
                const float* __restrict__ out, float* __restrict__ res) {
  __shared__ short lh[CT * 1024];   // 16 KB: hi  frags for chunk
  __shared__ short lm[CT * 1024];   // 16 KB: mid frags for chunk
  const int tid = threadIdx.x;
  const int wave = tid >> 6;
  const int lane = tid & 63;
  const int i0 = blockIdx.x * 64;                    // 4 i-tiles per block
  const int jbase = blockIdx.y * (B_ROWS / JSPLIT);  // 1024 j-rows = 64 tiles

  // A-fragments for 4 i-tiles, 2 k-steps, hi+mid (64 VGPRs)
  short8 Ah[4][2], Am[4][2];
#pragma unroll
  for (int it = 0; it < 4; ++it) {
    const int It = (i0 >> 4) + it;
#pragma unroll
    for (int q = 0; q < 2; ++q) {
      Ah[it][q] = *(const short8*)(vph + (size_t)It * 1024 + q * 512 + lane * 8);
      Am[it][q] = *(const short8*)(vpm + (size_t)It * 1024 + q * 512 + lane * 8);
    }
  }

  for (int c = 0; c < (B_ROWS / JSPLIT / 16) / CT; ++c) {   // 8 chunks
    const int Jt0 = (jbase >> 4) + c * CT;
    __syncthreads();
    // stage chunk: waves 0,1 -> hi halves; waves 2,3 -> mid halves (8 KB each)
    {
      const short* src = (wave < 2 ? vph : vpm) + (size_t)Jt0 * 1024 + (wave & 1) * 4096;
      short* dst = (wave < 2 ? lh : lm) + (wave & 1) * 4096;
#pragma unroll
      for (int u = 0; u < 8; ++u) {
        __builtin_amdgcn_global_load_lds(
            (const __attribute__((address_space(1))) void*)(src + u * 512 + lane * 8),
            (__attribute__((address_space(3))) void*)(dst + u * 512), 16, 0, 0);
      }
    }
    __syncthreads();

    // each wave: 2 j-tiles of the chunk
#pragma unroll
    for (int t = 0; t < 2; ++t) {
      const int jt = wave * 2 + t;
      const int j0 = jbase + (c * CT + jt) * 16;
      short8 Bh0 = *(const short8*)(lh + jt * 1024 + lane * 8);
      short8 Bh1 = *(const short8*)(lh + jt * 1024 + 512 + lane * 8);
      short8 Bm0 = *(const short8*)(lm + jt * 1024 + lane * 8);
      short8 Bm1 = *(const short8*)(lm + jt * 1024 + 512 + lane * 8);
#pragma unroll
      for (int it = 0; it < 4; ++it) {
        f32x4 g = {0.f, 0.f, 0.f, 0.f};
        g = __builtin_amdgcn_mfma_f32_16x16x32_bf16(Ah[it][0], Bh0, g, 0, 0, 0);
        g = __builtin_amdgcn_mfma_f32_16x16x32_bf16(Ah[it][1], Bh1, g, 0, 0, 0);
        g = __builtin_amdgcn_mfma_f32_16x16x32_bf16(Ah[it][0], Bm0, g, 0, 0, 0);
        g = __builtin_amdgcn_mfma_f32_16x16x32_bf16(Ah[it][1], Bm1, g, 0, 0, 0);
        g = __builtin_amdgcn_mfma_f32_16x16x32_bf16(Am[it][0], Bh0, g, 0, 0, 0);
        g = __builtin_amdgcn_mfma_f32_16x16x32_bf16(Am[it][1], Bh1, g, 0, 0, 0);
#pragma unroll
        for (int r = 0; r < 4; ++r) {
          const float gg = g[r];
          if (gg * gg >= THRESH) {   // fid = (v_i . v_j)^2 >= 0.9
            const int i = i0 + it * 16 + (lane >> 4) * 4 + r;
            const int j = j0 + (lane & 15);
            if (i != j) {
              const float* __restrict__ oj = out + (size_t)j * D_OUT;
              float* __restrict__ ri = res + (size_t)i * D_OUT;
              for (int k = 0; k < D_OUT; ++k) atomicAdd(&ri[k], oj[k]);
            }
          }
        }
      }
    }
  }
}

// ---------------- launch ----------------
extern "C" void kernel_launch(void* const* d_in, const int* in_sizes, int n_in,
                              void* d_out, int out_size, void* d_ws, size_t ws_size,
                              hipStream_t stream) {
  const float* x  = (const float*)d_in[0];
  const float* W1 = (const float*)d_in[1];
  const float* b1 = (const float*)d_in[2];
  const float* W2 = (const float*)d_in[3];
  const float* b2 = (const float*)d_in[4];
  const float* W3 = (const float*)d_in[5];
  const float* b3 = (const float*)d_in[6];
  float* res = (float*)d_out;

  char* ws = (char*)d_ws;
  float* h1    = (float*)ws;                                            // 16 MB
  float* h2    = (float*)(ws + (size_t)B_ROWS * H1_DIM * 4);            //  8 MB
  float* out   = (float*)(ws + (size_t)B_ROWS * (H1_DIM + H2_DIM) * 4); //  2 MB
  float* norms = (float*)((char*)out + (size_t)B_ROWS * D_OUT * 4);     // 32 KB
  // packed bf16 hi/mid fragment arrays reuse h1 space (dead after gemm2)
  short* vph = (short*)h1;                                              // 1 MB
  short* vpm = (short*)(ws + (size_t)B_ROWS * D_OUT * 2);               // 1 MB

  gemm_bias_act<true ><<<dim3(64, 8), 256, 0, stream>>>(x,  W1, b1, h1, D_IN,   H1_DIM);
  gemm_bias_act<true ><<<dim3(64, 4), 256, 0, stream>>>(h1, W2, b2, h2, H1_DIM, H2_DIM);
  gemm_bias_act<false><<<dim3(64, 1), 256, 0, stream>>>(h2, W3, b3, out, H2_DIM, D_OUT);
  row_norms<<<B_ROWS / 4, 256, 0, stream>>>(out, norms);
  pack_split<<<(B_ROWS * D_OUT / 8) / 256, 256, 0, stream>>>(out, norms, vph, vpm);
  zero_out<<<(B_ROWS * D_OUT) / 1024, 256, 0, stream>>>((float4*)res);
  gram_accum<<<dim3(B_ROWS / 64, JSPLIT), 256, 0, stream>>>(vph, vpm, out, res);
}

// Round 4
// 155.858 us; speedup vs baseline: 7.4991x; 1.4031x over previous
//
#include <hip/hip_runtime.h>
#include <hip/hip_bf16.h>
#include <math.h>

// Problem dims (fixed by reference)
#define B_ROWS 8192
#define D_IN   256
#define H1_DIM 512
#define H2_DIM 256
#define D_OUT  64
#define EPSF   1e-12f
#define THRESH 0.9f

typedef __attribute__((ext_vector_type(8))) short short8;   // 8 bf16 = 4 VGPR
typedef __attribute__((ext_vector_type(4))) float f32x4;

// ---------------- bf16 hi/mid split of 8 floats, fragment-major packing ----------------
// frag layout (16x16x32 MFMA A/B): tile I, kstep q, lane l, elem e
//   row = I*16 + (l&15), k = q*32 + (l>>4)*8 + e
// flat short index = ((I*(C/32) + q)*64 + lane)*8 + e   == t*8 + e
__device__ inline void pack8(const float* __restrict__ src, short* __restrict__ dh,
                             short* __restrict__ dm, int t, int C, int lgq) {
  const int lane = t & 63;
  const int g = t >> 6;
  const int q = g & ((1 << lgq) - 1);
  const int I = g >> lgq;
  const int row = I * 16 + (lane & 15);
  const int k0 = q * 32 + ((lane >> 4) << 3);
  const float* p = src + (size_t)row * C + k0;
  float4 a = *(const float4*)p;
  float4 b = *(const float4*)(p + 4);
  float v[8] = {a.x, a.y, a.z, a.w, b.x, b.y, b.z, b.w};
  short h8[8], m8[8];
#pragma unroll
  for (int e = 0; e < 8; ++e) {
    __hip_bfloat16 h = __float2bfloat16(v[e]);
    float hf = __bfloat162float(h);
    __hip_bfloat16 m = __float2bfloat16(v[e] - hf);
    h8[e] = *(short*)&h;
    m8[e] = *(short*)&m;
  }
  *(short8*)(dh + (size_t)t * 8) = *(short8*)h8;
  *(short8*)(dm + (size_t)t * 8) = *(short8*)m8;
}

__global__ __launch_bounds__(256)
void pack_a(const float* __restrict__ src, short* __restrict__ dh,
            short* __restrict__ dm, int C, int lgq) {
  pack8(src, dh, dm, blockIdx.x * 256 + threadIdx.x, C, lgq);
}

__global__ __launch_bounds__(256)
void pack_weights(const float* __restrict__ W1, const float* __restrict__ W2,
                  const float* __restrict__ W3,
                  short* w1h, short* w1m, short* w2h, short* w2m,
                  short* w3h, short* w3m) {
  const int b = blockIdx.x;
  if (b < 64)       pack8(W1, w1h, w1m, b * 256 + threadIdx.x, 256, 3);
  else if (b < 128) pack8(W2, w2h, w2m, (b - 64) * 256 + threadIdx.x, 512, 4);
  else              pack8(W3, w3h, w3m, (b - 128) * 256 + threadIdx.x, 256, 3);
}

// ---------------- MFMA GEMM: C[M,N] = act(A[M,K] @ B[N,K]^T + bias) ----------------
// A,B pre-packed bf16 hi/mid fragment-major. Split product: AhBh + AhBm + AmBh.
// Block: 128 rows x (32*JT) cols, 4 waves (2x2), wave = 4 i-tiles x JT j-tiles.
// PACK epilogue: tanh + split + write fragment-major hi/mid for the NEXT gemm.
template<int KSTEPS, int JT, bool PACK>
__global__ __launch_bounds__(256)
void mfma_gemm(const short* __restrict__ pAh, const short* __restrict__ pAm,
               const short* __restrict__ pBh, const short* __restrict__ pBm,
               const float* __restrict__ bias, float* __restrict__ Cout,
               short* __restrict__ dh, short* __restrict__ dm, int N) {
  constexpr int BTJ = 2 * JT;            // B tiles per block
  constexpr int NITEMS = 16 + 2 * BTJ;   // stage instrs per kstep (A:16, B:2*BTJ)
  constexpr int PER_WAVE = NITEMS / 4;
  constexpr int WCOL = 16 * JT + 4;      // padded wbuf row (16B-aligned stride)
  __shared__ __align__(16) short smAh[2][8 * 512];
  __shared__ __align__(16) short smAm[2][8 * 512];
  __shared__ __align__(16) short smBh[2][BTJ * 512];
  __shared__ __align__(16) short smBm[2][BTJ * 512];
  constexpr int WB = PACK ? 4 * 64 * WCOL : 4;
  __shared__ __align__(16) float wbuf[WB];

  const int tid = threadIdx.x;
  const int wave = tid >> 6, lane = tid & 63;
  const int wi = wave >> 1, wj = wave & 1;
  const int bIt0 = blockIdx.x * 8;
  const int bJt0 = blockIdx.y * BTJ;

  f32x4 acc[4][JT];
#pragma unroll
  for (int a = 0; a < 4; ++a)
#pragma unroll
    for (int b = 0; b < JT; ++b) acc[a][b] = (f32x4){0.f, 0.f, 0.f, 0.f};

  auto stage = [&](int q, int bf) {
#pragma unroll
    for (int u = 0; u < PER_WAVE; ++u) {
      const int item = wave * PER_WAVE + u;   // wave-uniform
      const short* src;
      short* dst;
      if (item < 16) {
        const int t = item >> 1;
        const int m = item & 1;
        src = (m ? pAm : pAh) + ((size_t)(bIt0 + t) * KSTEPS + q) * 512;
        dst = (m ? smAm : smAh)[bf] + t * 512;
      } else {
        const int e = item - 16;
        const int t = e >> 1;
        const int m = e & 1;
        src = (m ? pBm : pBh) + ((size_t)(bJt0 + t) * KSTEPS + q) * 512;
        dst = (m ? smBm : smBh)[bf] + t * 512;
      }
      __builtin_amdgcn_global_load_lds(
          (const __attribute__((address_space(1))) void*)(src + lane * 8),
          (__attribute__((address_space(3))) void*)dst, 16, 0, 0);
    }
  };

  stage(0, 0);
  for (int q = 0; q < KSTEPS; ++q) {
    __syncthreads();                         // staged q visible; prev reads drained
    if (q + 1 < KSTEPS) stage(q + 1, (q + 1) & 1);
    const int bf = q & 1;
    short8 Ah[4], Am[4];
#pragma unroll
    for (int it = 0; it < 4; ++it) {
      Ah[it] = *(const short8*)(smAh[bf] + (wi * 4 + it) * 512 + lane * 8);
      Am[it] = *(const short8*)(smAm[bf] + (wi * 4 + it) * 512 + lane * 8);
    }
    short8 Bh[JT], Bm[JT];
#pragma unroll
    for (int jt = 0; jt < JT; ++jt) {
      Bh[jt] = *(const short8*)(smBh[bf] + (wj * JT + jt) * 512 + lane * 8);
      Bm[jt] = *(const short8*)(smBm[bf] + (wj * JT + jt) * 512 + lane * 8);
    }
#pragma unroll
    for (int it = 0; it < 4; ++it)
#pragma unroll
      for (int jt = 0; jt < JT; ++jt) {
        acc[it][jt] = __builtin_amdgcn_mfma_f32_16x16x32_bf16(Ah[it], Bh[jt], acc[it][jt], 0, 0, 0);
        acc[it][jt] = __builtin_amdgcn_mfma_f32_16x16x32_bf16(Ah[it], Bm[jt], acc[it][jt], 0, 0, 0);
        acc[it][jt] = __builtin_amdgcn_mfma_f32_16x16x32_bf16(Am[it], Bh[jt], acc[it][jt], 0, 0, 0);
      }
  }

  float bv[JT];
#pragma unroll
  for (int jt = 0; jt < JT; ++jt)
    bv[jt] = bias[(bJt0 + wj * JT + jt) * 16 + (lane & 15)];

  if constexpr (PACK) {
    // C/D layout: col = lane&15, row = (lane>>4)*4 + r  -> wave-local LDS transpose
#pragma unroll
    for (int it = 0; it < 4; ++it)
#pragma unroll
      for (int jt = 0; jt < JT; ++jt)
#pragma unroll
        for (int r = 0; r < 4; ++r) {
          const float val = tanhf(acc[it][jt][r] + bv[jt]);
          const int row_l = it * 16 + (lane >> 4) * 4 + r;
          const int col_l = jt * 16 + (lane & 15);
          wbuf[(wave * 64 + row_l) * WCOL + col_l] = val;
        }
    __syncthreads();
    constexpr int QLMAX = JT / 2 ? JT / 2 : 1;   // JT=4 -> 2, JT=2 -> 1
#pragma unroll
    for (int itl = 0; itl < 4; ++itl)
#pragma unroll
      for (int ql = 0; ql < QLMAX; ++ql) {
        const int row_l = itl * 16 + (lane & 15);
        const int kl = ql * 32 + ((lane >> 4) << 3);
        const float* wp = &wbuf[(wave * 64 + row_l) * WCOL + kl];
        float4 a = *(const float4*)wp;
        float4 b = *(const float4*)(wp + 4);
        float v[8] = {a.x, a.y, a.z, a.w, b.x, b.y, b.z, b.w};
        short h8[8], m8[8];
#pragma unroll
        for (int e = 0; e < 8; ++e) {
          __hip_bfloat16 h = __float2bfloat16(v[e]);
          float hf = __bfloat162float(h);
          __hip_bfloat16 m = __float2bfloat16(v[e] - hf);
          h8[e] = *(short*)&h;
          m8[e] = *(short*)&m;
        }
        const int ItG = bIt0 + wi * 4 + itl;
        const int qG = (((bJt0 + wj * JT) * 16) + ql * 32) >> 5;
        const size_t off = ((size_t)(ItG * (N >> 5) + qG) * 64 + lane) * 8;
        *(short8*)(dh + off) = *(short8*)h8;
        *(short8*)(dm + off) = *(short8*)m8;
      }
  } else {
#pragma unroll
    for (int it = 0; it < 4; ++it)
#pragma unroll
      for (int jt = 0; jt < JT; ++jt)
#pragma unroll
        for (int r = 0; r < 4; ++r) {
          const int row = (bIt0 + wi * 4 + it) * 16 + (lane >> 4) * 4 + r;
          const int col = (bJt0 + wj * JT + jt) * 16 + (lane & 15);
          Cout[(size_t)row * N + col] = acc[it][jt][r] + bv[jt];
        }
  }
}

// ---------------- row norms ----------------
__global__ __launch_bounds__(256)
void row_norms(const float* __restrict__ out, float* __restrict__ norms) {
  const int wave = threadIdx.x >> 6;
  const int lane = threadIdx.x & 63;
  const int row = blockIdx.x * 4 + wave;
  float v = out[(size_t)row * D_OUT + lane];
  float s = v * v;
#pragma unroll
  for (int m = 32; m; m >>= 1) s += __shfl_xor(s, m, 64);
  if (lane == 0) norms[row] = sqrtf(s);
}

// ---------------- pack normalized rows (for gram) ----------------
__global__ __launch_bounds__(256)
void pack_split(const float* __restrict__ out, const float* __restrict__ norms,
                short* __restrict__ vph, short* __restrict__ vpm) {
  const int t = blockIdx.x * 256 + threadIdx.x;
  const int lane = t & 63;
  const int q = (t >> 6) & 1;
  const int J = t >> 7;
  const int row = J * 16 + (lane & 15);
  const int k0 = q * 32 + ((lane >> 4) << 3);
  const float inv = 1.0f / (norms[row] + EPSF);
  float4 a = *(const float4*)(out + (size_t)row * D_OUT + k0);
  float4 b = *(const float4*)(out + (size_t)row * D_OUT + k0 + 4);
  float vals[8] = {a.x, a.y, a.z, a.w, b.x, b.y, b.z, b.w};
  short h8[8], m8[8];
#pragma unroll
  for (int e = 0; e < 8; ++e) {
    float x = vals[e] * inv;
    __hip_bfloat16 h = __float2bfloat16(x);
    float hf = __bfloat162float(h);
    __hip_bfloat16 m = __float2bfloat16(x - hf);
    h8[e] = *(short*)&h;
    m8[e] = *(short*)&m;
  }
  *(short8*)(vph + (size_t)t * 8) = *(short8*)h8;
  *(short8*)(vpm + (size_t)t * 8) = *(short8*)m8;
}

// ---------------- zero d_out ----------------
__global__ __launch_bounds__(256)
void zero_out(float4* __restrict__ res) {
  res[blockIdx.x * 256 + threadIdx.x] = make_float4(0.f, 0.f, 0.f, 0.f);
}

// ---------------- MFMA Gram + threshold + sparse accumulate ----------------
#define JSPLIT 8
#define CT 8

__global__ __launch_bounds__(256)
void gram_accum(const short* __restrict__ vph, const short* __restrict__ vpm,
                const float* __restrict__ out, float* __restrict__ res) {
  __shared__ short lh[CT * 1024];
  __shared__ short lm[CT * 1024];
  const int tid = threadIdx.x;
  const int wave = tid >> 6;
  const int lane = tid & 63;
  const int i0 = blockIdx.x * 64;
  const int jbase = blockIdx.y * (B_ROWS / JSPLIT);

  short8 Ah[4][2], Am[4][2];
#pragma unroll
  for (int it = 0; it < 4; ++it) {
    const int It = (i0 >> 4) + it;
#pragma unroll
    for (int q = 0; q < 2; ++q) {
      Ah[it][q] = *(const short8*)(vph + (size_t)It * 1024 + q * 512 + lane * 8);
      Am[it][q] = *(const short8*)(vpm + (size_t)It * 1024 + q * 512 + lane * 8);
    }
  }

  for (int c = 0; c < (B_ROWS / JSPLIT / 16) / CT; ++c) {
    const int Jt0 = (jbase >> 4) + c * CT;
    __syncthreads();
    {
      const short* src = (wave < 2 ? vph : vpm) + (size_t)Jt0 * 1024 + (wave & 1) * 4096;
      short* dst = (wave < 2 ? lh : lm) + (wave & 1) * 4096;
#pragma unroll
      for (int u = 0; u < 8; ++u) {
        __builtin_amdgcn_global_load_lds(
            (const __attribute__((address_space(1))) void*)(src + u * 512 + lane * 8),
            (__attribute__((address_space(3))) void*)(dst + u * 512), 16, 0, 0);
      }
    }
    __syncthreads();

#pragma unroll
    for (int t = 0; t < 2; ++t) {
      const int jt = wave * 2 + t;
      const int j0 = jbase + (c * CT + jt) * 16;
      short8 Bh0 = *(const short8*)(lh + jt * 1024 + lane * 8);
      short8 Bh1 = *(const short8*)(lh + jt * 1024 + 512 + lane * 8);
      short8 Bm0 = *(const short8*)(lm + jt * 1024 + lane * 8);
      short8 Bm1 = *(const short8*)(lm + jt * 1024 + 512 + lane * 8);
#pragma unroll
      for (int it = 0; it < 4; ++it) {
        f32x4 g = {0.f, 0.f, 0.f, 0.f};
        g = __builtin_amdgcn_mfma_f32_16x16x32_bf16(Ah[it][0], Bh0, g, 0, 0, 0);
        g = __builtin_amdgcn_mfma_f32_16x16x32_bf16(Ah[it][1], Bh1, g, 0, 0, 0);
        g = __builtin_amdgcn_mfma_f32_16x16x32_bf16(Ah[it][0], Bm0, g, 0, 0, 0);
        g = __builtin_amdgcn_mfma_f32_16x16x32_bf16(Ah[it][1], Bm1, g, 0, 0, 0);
        g = __builtin_amdgcn_mfma_f32_16x16x32_bf16(Am[it][0], Bh0, g, 0, 0, 0);
        g = __builtin_amdgcn_mfma_f32_16x16x32_bf16(Am[it][1], Bh1, g, 0, 0, 0);
#pragma unroll
        for (int r = 0; r < 4; ++r) {
          const float gg = g[r];
          if (gg * gg >= THRESH) {
            const int i = i0 + it * 16 + (lane >> 4) * 4 + r;
            const int j = j0 + (lane & 15);
            if (i != j) {
              const float* __restrict__ oj = out + (size_t)j * D_OUT;
              float* __restrict__ ri = res + (size_t)i * D_OUT;
              for (int k = 0; k < D_OUT; ++k) atomicAdd(&ri[k], oj[k]);
            }
          }
        }
      }
    }
  }
}

// ---------------- launch ----------------
#define MB (1024 * 1024)

extern "C" void kernel_launch(void* const* d_in, const int* in_sizes, int n_in,
                              void* d_out, int out_size, void* d_ws, size_t ws_size,
                              hipStream_t stream) {
  const float* x  = (const float*)d_in[0];
  const float* W1 = (const float*)d_in[1];
  const float* b1 = (const float*)d_in[2];
  const float* W2 = (const float*)d_in[3];
  const float* b2 = (const float*)d_in[4];
  const float* W3 = (const float*)d_in[5];
  const float* b3 = (const float*)d_in[6];
  float* res = (float*)d_out;

  char* ws = (char*)d_ws;
  // R1 (8 MB): xh/xm, later reused as h2h/h2m
  short* xh  = (short*)(ws + 0 * MB);
  short* xm  = (short*)(ws + 4 * MB);
  short* h2h = (short*)(ws + 0 * MB);
  short* h2m = (short*)(ws + 4 * MB);
  // R2 (16 MB): h1h/h1m, later reused for out/norms/vph/vpm
  short* h1h = (short*)(ws + 8 * MB);
  short* h1m = (short*)(ws + 16 * MB);
  float* out   = (float*)(ws + 8 * MB);
  float* norms = (float*)(ws + 10 * MB);
  short* vph   = (short*)(ws + 11 * MB);
  short* vpm   = (short*)(ws + 12 * MB);
  // R3: packed weights (live all along)
  short* w1h = (short*)(ws + 24 * MB);
  short* w1m = (short*)(ws + 24 * MB + 256 * 1024);
  short* w2h = (short*)(ws + 24 * MB + 512 * 1024);
  short* w2m = (short*)(ws + 24 * MB + 768 * 1024);
  short* w3h = (short*)(ws + 25 * MB);
  short* w3m = (short*)(ws + 25 * MB + 32 * 1024);

  pack_a<<<1024, 256, 0, stream>>>(x, xh, xm, 256, 3);
  pack_weights<<<136, 256, 0, stream>>>(W1, W2, W3, w1h, w1m, w2h, w2m, w3h, w3m);
  // gemm1: [8192,256] @ W1^T -> tanh -> packed h1 (N=512)
  mfma_gemm<8, 4, true><<<dim3(64, 4), 256, 0, stream>>>(
      xh, xm, w1h, w1m, b1, nullptr, h1h, h1m, H1_DIM);
  // gemm2: [8192,512] @ W2^T -> tanh -> packed h2 (N=256)
  mfma_gemm<16, 2, true><<<dim3(64, 4), 256, 0, stream>>>(
      h1h, h1m, w2h, w2m, b2, nullptr, h2h, h2m, H2_DIM);
  // gemm3: [8192,256] @ W3^T + b -> fp32 out (N=64)
  mfma_gemm<8, 2, false><<<dim3(64, 1), 256, 0, stream>>>(
      h2h, h2m, w3h, w3m, b3, out, nullptr, nullptr, D_OUT);
  row_norms<<<B_ROWS / 4, 256, 0, stream>>>(out, norms);
  pack_split<<<256, 256, 0, stream>>>(out, norms, vph, vpm);
  zero_out<<<(B_ROWS * D_OUT) / 1024, 256, 0, stream>>>((float4*)res);
  gram_accum<<<dim3(B_ROWS / 64, JSPLIT), 256, 0, stream>>>(vph, vpm, out, res);
}

// Round 5
// 148.447 us; speedup vs baseline: 7.8735x; 1.0499x over previous
//
#include <hip/hip_runtime.h>
#include <hip/hip_bf16.h>
#include <math.h>

// Problem dims (fixed by reference)
#define B_ROWS 8192
#define D_IN   256
#define H1_DIM 512
#define H2_DIM 256
#define D_OUT  64
#define EPSF   1e-12f
#define THRESH 0.9f

typedef __attribute__((ext_vector_type(8))) short short8;   // 8 bf16 = 4 VGPR
typedef __attribute__((ext_vector_type(4))) float f32x4;

// ---------------- bf16 hi/mid split, fragment-major packing ----------------
// frag layout (16x16x32 MFMA A/B): tile I, kstep q, lane l, elem e
//   row = I*16 + (l&15), k = q*32 + (l>>4)*8 + e
// flat short index = ((I*(C/32) + q)*64 + lane)*8 + e == t*8 + e
__device__ inline void pack8(const float* __restrict__ src, short* __restrict__ dh,
                             short* __restrict__ dm, int t, int C, int lgq) {
  const int lane = t & 63;
  const int g = t >> 6;
  const int q = g & ((1 << lgq) - 1);
  const int I = g >> lgq;
  const int row = I * 16 + (lane & 15);
  const int k0 = q * 32 + ((lane >> 4) << 3);
  const float* p = src + (size_t)row * C + k0;
  float4 a = *(const float4*)p;
  float4 b = *(const float4*)(p + 4);
  float v[8] = {a.x, a.y, a.z, a.w, b.x, b.y, b.z, b.w};
  short h8[8], m8[8];
#pragma unroll
  for (int e = 0; e < 8; ++e) {
    __hip_bfloat16 h = __float2bfloat16(v[e]);
    float hf = __bfloat162float(h);
    __hip_bfloat16 m = __float2bfloat16(v[e] - hf);
    h8[e] = *(short*)&h;
    m8[e] = *(short*)&m;
  }
  *(short8*)(dh + (size_t)t * 8) = *(short8*)h8;
  *(short8*)(dm + (size_t)t * 8) = *(short8*)m8;
}

// one launch: pack x, W1, W2, W3
__global__ __launch_bounds__(256)
void pack_inputs(const float* __restrict__ x, const float* __restrict__ W1,
                 const float* __restrict__ W2, const float* __restrict__ W3,
                 short* xh, short* xm, short* w1h, short* w1m,
                 short* w2h, short* w2m, short* w3h, short* w3m) {
  const int b = blockIdx.x;
  const int tid = threadIdx.x;
  if (b < 1024)       pack8(x,  xh,  xm,  b * 256 + tid, 256, 3);
  else if (b < 1088)  pack8(W1, w1h, w1m, (b - 1024) * 256 + tid, 256, 3);
  else if (b < 1152)  pack8(W2, w2h, w2m, (b - 1088) * 256 + tid, 512, 4);
  else                pack8(W3, w3h, w3m, (b - 1152) * 256 + tid, 256, 3);
}

// ---------------- MFMA GEMM: C[M,N] = act(A[M,K] @ B[N,K]^T + bias) ----------------
// A,B pre-packed bf16 hi/mid fragment-major. Split product: AhBh + AhBm + AmBh.
// Block: 128 rows x (32*JT) cols, 4 waves (2x2), wave = 4 i-tiles x JT j-tiles.
// MODE 1: tanh + split-pack epilogue (writes dh/dm for the next gemm).
// MODE 2: final layer — write fp32 Cout, compute row norms in-block, write
//         NORMALIZED split-pack dh/dm (= vph/vpm for the gram stage).
template<int KSTEPS, int JT, int MODE>
__global__ __launch_bounds__(256)
void mfma_gemm(const short* __restrict__ pAh, const short* __restrict__ pAm,
               const short* __restrict__ pBh, const short* __restrict__ pBm,
               const float* __restrict__ bias, float* __restrict__ Cout,
               short* __restrict__ dh, short* __restrict__ dm, int N) {
  constexpr int BTJ = 2 * JT;            // B tiles per block
  constexpr int NITEMS = 16 + 2 * BTJ;   // stage instrs per kstep (A:16, B:2*BTJ)
  constexpr int PER_WAVE = NITEMS / 4;
  constexpr int WCOL = 16 * JT + 4;      // padded wbuf row stride
  __shared__ __align__(16) short smAh[2][8 * 512];
  __shared__ __align__(16) short smAm[2][8 * 512];
  __shared__ __align__(16) short smBh[2][BTJ * 512];
  __shared__ __align__(16) short smBm[2][BTJ * 512];
  __shared__ __align__(16) float wbuf[4 * 64 * WCOL];
  __shared__ float nsum[2][128];
  __shared__ float invn[128];

  const int tid = threadIdx.x;
  const int wave = tid >> 6, lane = tid & 63;
  const int wi = wave >> 1, wj = wave & 1;
  const int bIt0 = blockIdx.x * 8;
  const int bJt0 = blockIdx.y * BTJ;

  f32x4 acc[4][JT];
#pragma unroll
  for (int a = 0; a < 4; ++a)
#pragma unroll
    for (int b = 0; b < JT; ++b) acc[a][b] = (f32x4){0.f, 0.f, 0.f, 0.f};

  auto stage = [&](int q, int bf) {
#pragma unroll
    for (int u = 0; u < PER_WAVE; ++u) {
      const int item = wave * PER_WAVE + u;   // wave-uniform
      const short* src;
      short* dst;
      if (item < 16) {
        const int t = item >> 1;
        const int m = item & 1;
        src = (m ? pAm : pAh) + ((size_t)(bIt0 + t) * KSTEPS + q) * 512;
        dst = (m ? smAm : smAh)[bf] + t * 512;
      } else {
        const int e = item - 16;
        const int t = e >> 1;
        const int m = e & 1;
        src = (m ? pBm : pBh) + ((size_t)(bJt0 + t) * KSTEPS + q) * 512;
        dst = (m ? smBm : smBh)[bf] + t * 512;
      }
      __builtin_amdgcn_global_load_lds(
          (const __attribute__((address_space(1))) void*)(src + lane * 8),
          (__attribute__((address_space(3))) void*)dst, 16, 0, 0);
    }
  };

  stage(0, 0);
  for (int q = 0; q < KSTEPS; ++q) {
    __syncthreads();
    if (q + 1 < KSTEPS) stage(q + 1, (q + 1) & 1);
    const int bf = q & 1;
    short8 Ah[4], Am[4];
#pragma unroll
    for (int it = 0; it < 4; ++it) {
      Ah[it] = *(const short8*)(smAh[bf] + (wi * 4 + it) * 512 + lane * 8);
      Am[it] = *(const short8*)(smAm[bf] + (wi * 4 + it) * 512 + lane * 8);
    }
    short8 Bh[JT], Bm[JT];
#pragma unroll
    for (int jt = 0; jt < JT; ++jt) {
      Bh[jt] = *(const short8*)(smBh[bf] + (wj * JT + jt) * 512 + lane * 8);
      Bm[jt] = *(const short8*)(smBm[bf] + (wj * JT + jt) * 512 + lane * 8);
    }
#pragma unroll
    for (int it = 0; it < 4; ++it)
#pragma unroll
      for (int jt = 0; jt < JT; ++jt) {
        acc[it][jt] = __builtin_amdgcn_mfma_f32_16x16x32_bf16(Ah[it], Bh[jt], acc[it][jt], 0, 0, 0);
        acc[it][jt] = __builtin_amdgcn_mfma_f32_16x16x32_bf16(Ah[it], Bm[jt], acc[it][jt], 0, 0, 0);
        acc[it][jt] = __builtin_amdgcn_mfma_f32_16x16x32_bf16(Am[it], Bh[jt], acc[it][jt], 0, 0, 0);
      }
  }

  float bv[JT];
#pragma unroll
  for (int jt = 0; jt < JT; ++jt)
    bv[jt] = bias[(bJt0 + wj * JT + jt) * 16 + (lane & 15)];

  // C/D layout: col = lane&15, row = (lane>>4)*4 + r
  if constexpr (MODE == 1) {
#pragma unroll
    for (int it = 0; it < 4; ++it)
#pragma unroll
      for (int jt = 0; jt < JT; ++jt)
#pragma unroll
        for (int r = 0; r < 4; ++r) {
          const float val = tanhf(acc[it][jt][r] + bv[jt]);
          const int row_l = it * 16 + (lane >> 4) * 4 + r;
          const int col_l = jt * 16 + (lane & 15);
          wbuf[(wave * 64 + row_l) * WCOL + col_l] = val;
        }
    __syncthreads();
  } else {
    // final layer: raw value to wbuf + fp32 Cout + row-sumsq reduction
#pragma unroll
    for (int it = 0; it < 4; ++it)
#pragma unroll
      for (int r = 0; r < 4; ++r) {
        float sq = 0.f;
        const int row_l = it * 16 + (lane >> 4) * 4 + r;
#pragma unroll
        for (int jt = 0; jt < JT; ++jt) {
          const float val = acc[it][jt][r] + bv[jt];
          const int col_l = jt * 16 + (lane & 15);
          wbuf[(wave * 64 + row_l) * WCOL + col_l] = val;
          const int row = (bIt0 + wi * 4 + it) * 16 + (lane >> 4) * 4 + r;
          Cout[(size_t)row * N + wj * (16 * JT) + col_l] = val;
          sq = fmaf(val, val, sq);
        }
        // reduce across the 16 lanes sharing (lane>>4): masks 1,2,4,8
#pragma unroll
        for (int m = 1; m < 16; m <<= 1) sq += __shfl_xor(sq, m, 64);
        if ((lane & 15) == 0) nsum[wj][wi * 64 + row_l] = sq;
      }
    __syncthreads();
    if (tid < 128) invn[tid] = 1.0f / (sqrtf(nsum[0][tid] + nsum[1][tid]) + EPSF);
    __syncthreads();
  }

  // split-pack epilogue (both modes): wbuf -> fragment-major hi/mid
  constexpr int QLMAX = (JT / 2) ? (JT / 2) : 1;   // JT=4 -> 2, JT=2 -> 1
#pragma unroll
  for (int itl = 0; itl < 4; ++itl)
#pragma unroll
    for (int ql = 0; ql < QLMAX; ++ql) {
      const int row_l = itl * 16 + (lane & 15);
      const int kl = ql * 32 + ((lane >> 4) << 3);
      const float* wp = &wbuf[(wave * 64 + row_l) * WCOL + kl];
      const float scale = (MODE == 2) ? invn[wi * 64 + row_l] : 1.0f;
      float4 a = *(const float4*)wp;
      float4 b = *(const float4*)(wp + 4);
      float v[8] = {a.x, a.y, a.z, a.w, b.x, b.y, b.z, b.w};
      short h8[8], m8[8];
#pragma unroll
      for (int e = 0; e < 8; ++e) {
        const float sv = v[e] * scale;
        __hip_bfloat16 h = __float2bfloat16(sv);
        float hf = __bfloat162float(h);
        __hip_bfloat16 m = __float2bfloat16(sv - hf);
        h8[e] = *(short*)&h;
        m8[e] = *(short*)&m;
      }
      const int ItG = bIt0 + wi * 4 + itl;
      const int qG = (((bJt0 + wj * JT) * 16) + ql * 32) >> 5;
      const size_t off = ((size_t)(ItG * (N >> 5) + qG) * 64 + lane) * 8;
      *(short8*)(dh + off) = *(short8*)h8;
      *(short8*)(dm + off) = *(short8*)m8;
    }
}

// ---------------- zero d_out ----------------
__global__ __launch_bounds__(256)
void zero_out(float4* __restrict__ res) {
  res[blockIdx.x * 256 + threadIdx.x] = make_float4(0.f, 0.f, 0.f, 0.f);
}

// ---------------- MFMA Gram + threshold + sparse accumulate (v2) ----------------
// res[i] = sum_{j != i, (v_i.v_j)^2 >= 0.9} out[j]
// 128 i-rows per block in registers; double-buffered 128-row j-chunks in LDS.
#define JSPLIT 8
#define CT 8                      // j-tiles per chunk (128 j-rows)
#define NCHUNK (B_ROWS / JSPLIT / 16 / CT)   // 8

__global__ __launch_bounds__(256)
void gram_accum(const short* __restrict__ vph, const short* __restrict__ vpm,
                const float* __restrict__ out, float* __restrict__ res) {
  __shared__ __align__(16) short lh[2][CT * 1024];   // 2 x 16 KB
  __shared__ __align__(16) short lm[2][CT * 1024];   // 2 x 16 KB
  const int tid = threadIdx.x;
  const int wave = tid >> 6;
  const int lane = tid & 63;
  const int i0 = blockIdx.x * 128;                   // 8 i-tiles per block
  const int jbase = blockIdx.y * (B_ROWS / JSPLIT);  // 1024 j-rows

  // A-fragments: 8 i-tiles x 2 ksteps, hi+mid (128 VGPRs)
  short8 Ah[8][2], Am[8][2];
#pragma unroll
  for (int it = 0; it < 8; ++it) {
    const int It = (i0 >> 4) + it;
#pragma unroll
    for (int q = 0; q < 2; ++q) {
      Ah[it][q] = *(const short8*)(vph + (size_t)It * 1024 + q * 512 + lane * 8);
      Am[it][q] = *(const short8*)(vpm + (size_t)It * 1024 + q * 512 + lane * 8);
    }
  }

  auto stage = [&](int c, int bf) {
    const size_t base = ((size_t)(jbase >> 4) + c * CT) * 1024;
#pragma unroll
    for (int u = 0; u < 8; ++u) {
      const int item = wave * 8 + u;   // 0..31, wave-uniform
      const short* src;
      short* dst;
      if (item < 16) { src = vph + base + item * 512; dst = lh[bf] + item * 512; }
      else           { src = vpm + base + (item - 16) * 512; dst = lm[bf] + (item - 16) * 512; }
      __builtin_amdgcn_global_load_lds(
          (const __attribute__((address_space(1))) void*)(src + lane * 8),
          (__attribute__((address_space(3))) void*)dst, 16, 0, 0);
    }
  };

  stage(0, 0);
  for (int c = 0; c < NCHUNK; ++c) {
    __syncthreads();                       // chunk c staged; prior reads drained
    if (c + 1 < NCHUNK) stage(c + 1, (c + 1) & 1);
    const int bf = c & 1;
#pragma unroll
    for (int t = 0; t < 2; ++t) {
      const int jt = wave * 2 + t;
      const int j0 = jbase + (c * CT + jt) * 16;
      short8 Bh0 = *(const short8*)(lh[bf] + jt * 1024 + lane * 8);
      short8 Bh1 = *(const short8*)(lh[bf] + jt * 1024 + 512 + lane * 8);
      short8 Bm0 = *(const short8*)(lm[bf] + jt * 1024 + lane * 8);
      short8 Bm1 = *(const short8*)(lm[bf] + jt * 1024 + 512 + lane * 8);
#pragma unroll
      for (int it = 0; it < 8; ++it) {
        f32x4 g = {0.f, 0.f, 0.f, 0.f};
        g = __builtin_amdgcn_mfma_f32_16x16x32_bf16(Ah[it][0], Bh0, g, 0, 0, 0);
        g = __builtin_amdgcn_mfma_f32_16x16x32_bf16(Ah[it][1], Bh1, g, 0, 0, 0);
        g = __builtin_amdgcn_mfma_f32_16x16x32_bf16(Ah[it][0], Bm0, g, 0, 0, 0);
        g = __builtin_amdgcn_mfma_f32_16x16x32_bf16(Ah[it][1], Bm1, g, 0, 0, 0);
        g = __builtin_amdgcn_mfma_f32_16x16x32_bf16(Am[it][0], Bh0, g, 0, 0, 0);
        g = __builtin_amdgcn_mfma_f32_16x16x32_bf16(Am[it][1], Bh1, g, 0, 0, 0);
#pragma unroll
        for (int r = 0; r < 4; ++r) {
          const float gg = g[r];
          if (gg * gg >= THRESH) {   // fid = (v_i.v_j)^2 >= 0.9
            const int i = i0 + it * 16 + (lane >> 4) * 4 + r;
            const int j = j0 + (lane & 15);
            if (i != j) {
              const float* __restrict__ oj = out + (size_t)j * D_OUT;
              float* __restrict__ ri = res + (size_t)i * D_OUT;
              for (int k = 0; k < D_OUT; ++k) atomicAdd(&ri[k], oj[k]);
            }
          }
        }
      }
    }
  }
}

// ---------------- launch ----------------
#define MB (1024 * 1024)

extern "C" void kernel_launch(void* const* d_in, const int* in_sizes, int n_in,
                              void* d_out, int out_size, void* d_ws, size_t ws_size,
                              hipStream_t stream) {
  const float* x  = (const float*)d_in[0];
  const float* W1 = (const float*)d_in[1];
  const float* b1 = (const float*)d_in[2];
  const float* W2 = (const float*)d_in[3];
  const float* b2 = (const float*)d_in[4];
  const float* W3 = (const float*)d_in[5];
  const float* b3 = (const float*)d_in[6];
  float* res = (float*)d_out;

  char* ws = (char*)d_ws;
  // R1 (8 MB): xh/xm, later reused as h2h/h2m
  short* xh  = (short*)(ws + 0 * MB);
  short* xm  = (short*)(ws + 4 * MB);
  short* h2h = (short*)(ws + 0 * MB);
  short* h2m = (short*)(ws + 4 * MB);
  // R2 (16 MB): h1h/h1m, later reused for out/vph/vpm
  short* h1h = (short*)(ws + 8 * MB);
  short* h1m = (short*)(ws + 16 * MB);
  float* out = (float*)(ws + 8 * MB);
  short* vph = (short*)(ws + 11 * MB);
  short* vpm = (short*)(ws + 12 * MB);
  // R3: packed weights
  short* w1h = (short*)(ws + 24 * MB);
  short* w1m = (short*)(ws + 24 * MB + 256 * 1024);
  short* w2h = (short*)(ws + 24 * MB + 512 * 1024);
  short* w2m = (short*)(ws + 24 * MB + 768 * 1024);
  short* w3h = (short*)(ws + 25 * MB);
  short* w3m = (short*)(ws + 25 * MB + 32 * 1024);

  pack_inputs<<<1160, 256, 0, stream>>>(x, W1, W2, W3, xh, xm, w1h, w1m, w2h, w2m, w3h, w3m);
  // gemm1: [8192,256] @ W1^T -> tanh -> packed h1 (N=512)
  mfma_gemm<8, 4, 1><<<dim3(64, 4), 256, 0, stream>>>(
      xh, xm, w1h, w1m, b1, nullptr, h1h, h1m, H1_DIM);
  // gemm2: [8192,512] @ W2^T -> tanh -> packed h2 (N=256)
  mfma_gemm<16, 2, 1><<<dim3(64, 4), 256, 0, stream>>>(
      h1h, h1m, w2h, w2m, b2, nullptr, h2h, h2m, H2_DIM);
  // gemm3: [8192,256] @ W3^T + b -> fp32 out + normalized packed vph/vpm (N=64)
  mfma_gemm<8, 2, 2><<<dim3(64, 1), 256, 0, stream>>>(
      h2h, h2m, w3h, w3m, b3, out, vph, vpm, D_OUT);
  zero_out<<<(B_ROWS * D_OUT) / 1024, 256, 0, stream>>>((float4*)res);
  gram_accum<<<dim3(B_ROWS / 128, JSPLIT), 256, 0, stream>>>(vph, vpm, out, res);
}

// Round 6
// 125.521 us; speedup vs baseline: 9.3116x; 1.1826x over previous
//
#include <hip/hip_runtime.h>
#include <hip/hip_bf16.h>
#include <math.h>

// Problem dims (fixed by reference)
#define B_ROWS 8192
#define D_IN   256
#define H1_DIM 512
#define H2_DIM 256
#define D_OUT  64
#define EPSF   1e-12f
#define THRESH 0.9f

typedef __attribute__((ext_vector_type(8))) short short8;   // 8 bf16 = 4 VGPR
typedef __attribute__((ext_vector_type(4))) float f32x4;

// ---------------- bf16 hi/mid split, fragment-major packing ----------------
// frag layout (16x16x32 MFMA A/B): tile I, kstep q, lane l, elem e
//   row = I*16 + (l&15), k = q*32 + (l>>4)*8 + e
// flat short index = ((I*(C/32) + q)*64 + lane)*8 + e == t*8 + e
__device__ inline void pack8(const float* __restrict__ src, short* __restrict__ dh,
                             short* __restrict__ dm, int t, int C, int lgq) {
  const int lane = t & 63;
  const int g = t >> 6;
  const int q = g & ((1 << lgq) - 1);
  const int I = g >> lgq;
  const int row = I * 16 + (lane & 15);
  const int k0 = q * 32 + ((lane >> 4) << 3);
  const float* p = src + (size_t)row * C + k0;
  float4 a = *(const float4*)p;
  float4 b = *(const float4*)(p + 4);
  float v[8] = {a.x, a.y, a.z, a.w, b.x, b.y, b.z, b.w};
  short h8[8], m8[8];
#pragma unroll
  for (int e = 0; e < 8; ++e) {
    __hip_bfloat16 h = __float2bfloat16(v[e]);
    float hf = __bfloat162float(h);
    __hip_bfloat16 m = __float2bfloat16(v[e] - hf);
    h8[e] = *(short*)&h;
    m8[e] = *(short*)&m;
  }
  *(short8*)(dh + (size_t)t * 8) = *(short8*)h8;
  *(short8*)(dm + (size_t)t * 8) = *(short8*)m8;
}

// one launch: pack x, W1, W2, W3
__global__ __launch_bounds__(256)
void pack_inputs(const float* __restrict__ x, const float* __restrict__ W1,
                 const float* __restrict__ W2, const float* __restrict__ W3,
                 short* xh, short* xm, short* w1h, short* w1m,
                 short* w2h, short* w2m, short* w3h, short* w3m) {
  const int b = blockIdx.x;
  const int tid = threadIdx.x;
  if (b < 1024)       pack8(x,  xh,  xm,  b * 256 + tid, 256, 3);
  else if (b < 1088)  pack8(W1, w1h, w1m, (b - 1024) * 256 + tid, 256, 3);
  else if (b < 1152)  pack8(W2, w2h, w2m, (b - 1088) * 256 + tid, 512, 4);
  else                pack8(W3, w3h, w3m, (b - 1152) * 256 + tid, 256, 3);
}

// ---------------- MFMA GEMM: C[M,N] = act(A[M,K] @ B[N,K]^T + bias) ----------------
// 64-row x (32*JT)-col blocks, 4 waves (2x2), wave = 2 i-tiles x JT j-tiles.
// LDS: double-buffered staging UNION'd with the epilogue transpose buffer
// (staging dead after the K-loop) -> 48/32 KB => 2-3 blocks/CU co-resident.
// MODE 1: tanh + split-pack epilogue (writes dh/dm for the next gemm).
// MODE 2: final layer — zero `rz`, write fp32 Cout, row norms in-block,
//         write NORMALIZED split-pack dh/dm (= vph/vpm for the gram stage).
template<int KSTEPS, int JT, int MODE>
__global__ __launch_bounds__(256, 2)
void mfma_gemm(const short* __restrict__ pAh, const short* __restrict__ pAm,
               const short* __restrict__ pBh, const short* __restrict__ pBm,
               const float* __restrict__ bias, float* __restrict__ Cout,
               short* __restrict__ dh, short* __restrict__ dm, int N,
               float* __restrict__ rz) {
  constexpr int ITB = 4;                   // i-tiles per block (64 rows)
  constexpr int BTJ = 2 * JT;              // B tiles per block
  constexpr int NITEMS = 2 * ITB + 2 * BTJ;
  constexpr int PER_WAVE = NITEMS / 4;
  constexpr int WCOL = 16 * JT + 4;        // padded wbuf row stride (16B-aligned)
  union SM {
    struct {
      short Ah[2][ITB * 512];
      short Am[2][ITB * 512];
      short Bh[2][BTJ * 512];
      short Bm[2][BTJ * 512];
    } st;
    float wbuf[4 * 32 * WCOL];
  };
  __shared__ __align__(16) SM sm;
  __shared__ float nsum[2][64];
  __shared__ float invn[64];

  const int tid = threadIdx.x;
  const int wave = tid >> 6, lane = tid & 63;
  const int wi = wave >> 1, wj = wave & 1;
  const int bIt0 = blockIdx.x * ITB;
  const int bJt0 = blockIdx.y * BTJ;

  if constexpr (MODE == 2) {
    // zero the 64 res rows this block owns (res poisoned 0xAA by harness)
    float4* rz4 = (float4*)(rz + (size_t)blockIdx.x * 64 * 64);
#pragma unroll
    for (int u = 0; u < 4; ++u)
      rz4[u * 256 + tid] = make_float4(0.f, 0.f, 0.f, 0.f);
  }

  f32x4 acc[2][JT];
#pragma unroll
  for (int a = 0; a < 2; ++a)
#pragma unroll
    for (int b = 0; b < JT; ++b) acc[a][b] = (f32x4){0.f, 0.f, 0.f, 0.f};

  auto stage = [&](int q, int bf) {
#pragma unroll
    for (int u = 0; u < PER_WAVE; ++u) {
      const int item = wave * PER_WAVE + u;   // wave-uniform
      const short* src;
      short* dst;
      if (item < 2 * ITB) {
        const int t = item >> 1;
        const int m = item & 1;
        src = (m ? pAm : pAh) + ((size_t)(bIt0 + t) * KSTEPS + q) * 512;
        dst = (m ? sm.st.Am : sm.st.Ah)[bf] + t * 512;
      } else {
        const int e = item - 2 * ITB;
        const int t = e >> 1;
        const int m = e & 1;
        src = (m ? pBm : pBh) + ((size_t)(bJt0 + t) * KSTEPS + q) * 512;
        dst = (m ? sm.st.Bm : sm.st.Bh)[bf] + t * 512;
      }
      __builtin_amdgcn_global_load_lds(
          (const __attribute__((address_space(1))) void*)(src + lane * 8),
          (__attribute__((address_space(3))) void*)dst, 16, 0, 0);
    }
  };

  stage(0, 0);
  for (int q = 0; q < KSTEPS; ++q) {
    __syncthreads();
    if (q + 1 < KSTEPS) stage(q + 1, (q + 1) & 1);
    const int bf = q & 1;
    short8 Ah[2], Am[2];
#pragma unroll
    for (int it = 0; it < 2; ++it) {
      Ah[it] = *(const short8*)(sm.st.Ah[bf] + (wi * 2 + it) * 512 + lane * 8);
      Am[it] = *(const short8*)(sm.st.Am[bf] + (wi * 2 + it) * 512 + lane * 8);
    }
    short8 Bh[JT], Bm[JT];
#pragma unroll
    for (int jt = 0; jt < JT; ++jt) {
      Bh[jt] = *(const short8*)(sm.st.Bh[bf] + (wj * JT + jt) * 512 + lane * 8);
      Bm[jt] = *(const short8*)(sm.st.Bm[bf] + (wj * JT + jt) * 512 + lane * 8);
    }
#pragma unroll
    for (int it = 0; it < 2; ++it)
#pragma unroll
      for (int jt = 0; jt < JT; ++jt) {
        acc[it][jt] = __builtin_amdgcn_mfma_f32_16x16x32_bf16(Ah[it], Bh[jt], acc[it][jt], 0, 0, 0);
        acc[it][jt] = __builtin_amdgcn_mfma_f32_16x16x32_bf16(Ah[it], Bm[jt], acc[it][jt], 0, 0, 0);
        acc[it][jt] = __builtin_amdgcn_mfma_f32_16x16x32_bf16(Am[it], Bh[jt], acc[it][jt], 0, 0, 0);
      }
  }
  __syncthreads();   // staging dead; union region becomes wbuf

  float bv[JT];
#pragma unroll
  for (int jt = 0; jt < JT; ++jt)
    bv[jt] = bias[(bJt0 + wj * JT + jt) * 16 + (lane & 15)];

  // C/D layout: col = lane&15, row = (lane>>4)*4 + r
  if constexpr (MODE == 1) {
#pragma unroll
    for (int it = 0; it < 2; ++it)
#pragma unroll
      for (int jt = 0; jt < JT; ++jt)
#pragma unroll
        for (int r = 0; r < 4; ++r) {
          const float val = tanhf(acc[it][jt][r] + bv[jt]);
          const int row_l = it * 16 + (lane >> 4) * 4 + r;
          const int col_l = jt * 16 + (lane & 15);
          sm.wbuf[(wave * 32 + row_l) * WCOL + col_l] = val;
        }
    __syncthreads();
  } else {
#pragma unroll
    for (int it = 0; it < 2; ++it)
#pragma unroll
      for (int r = 0; r < 4; ++r) {
        float sq = 0.f;
        const int row_l = it * 16 + (lane >> 4) * 4 + r;
#pragma unroll
        for (int jt = 0; jt < JT; ++jt) {
          const float val = acc[it][jt][r] + bv[jt];
          const int col_l = jt * 16 + (lane & 15);
          sm.wbuf[(wave * 32 + row_l) * WCOL + col_l] = val;
          const int row = (bIt0 + wi * 2 + it) * 16 + (lane >> 4) * 4 + r;
          Cout[(size_t)row * N + wj * (16 * JT) + col_l] = val;
          sq = fmaf(val, val, sq);
        }
#pragma unroll
        for (int m = 1; m < 16; m <<= 1) sq += __shfl_xor(sq, m, 64);
        if ((lane & 15) == 0) nsum[wj][wi * 32 + row_l] = sq;
      }
    __syncthreads();
    if (tid < 64) invn[tid] = 1.0f / (sqrtf(nsum[0][tid] + nsum[1][tid]) + EPSF);
    __syncthreads();
  }

  // split-pack epilogue (both modes): wbuf -> fragment-major hi/mid
  constexpr int QLMAX = (JT >= 2) ? (JT / 2) : 1;
#pragma unroll
  for (int itl = 0; itl < 2; ++itl)
#pragma unroll
    for (int ql = 0; ql < QLMAX; ++ql) {
      const int row_l = itl * 16 + (lane & 15);          // [0,32)
      const int kl = ql * 32 + ((lane >> 4) << 3);
      const float* wp = &sm.wbuf[(wave * 32 + row_l) * WCOL + kl];
      const float scale = (MODE == 2) ? invn[wi * 32 + row_l] : 1.0f;
      float4 a = *(const float4*)wp;
      float4 b = *(const float4*)(wp + 4);
      float v[8] = {a.x, a.y, a.z, a.w, b.x, b.y, b.z, b.w};
      short h8[8], m8[8];
#pragma unroll
      for (int e = 0; e < 8; ++e) {
        const float sv = v[e] * scale;
        __hip_bfloat16 h = __float2bfloat16(sv);
        float hf = __bfloat162float(h);
        __hip_bfloat16 m = __float2bfloat16(sv - hf);
        h8[e] = *(short*)&h;
        m8[e] = *(short*)&m;
      }
      const int ItG = bIt0 + wi * 2 + itl;
      const int qG = (((bJt0 + wj * JT) * 16) + ql * 32) >> 5;
      const size_t off = ((size_t)(ItG * (N >> 5) + qG) * 64 + lane) * 8;
      *(short8*)(dh + off) = *(short8*)h8;
      *(short8*)(dm + off) = *(short8*)m8;
    }
}

// ---------------- MFMA Gram + threshold + sparse accumulate (v3) ----------------
// res[i] = sum_{j != i, (v_i.v_j)^2 >= 0.9} out[j]
// v3: threshold hoisted OUT of the MFMA region — per j-tile, 48 MFMAs run as a
// straight-line block (8 independent accumulator chains), then one rare-taken
// branch per i-tile (max over the 4 C-regs). No control flow between MFMAs.
#define JSPLIT 8
#define CT 8                                 // j-tiles per chunk (128 j-rows)
#define NCHUNK (B_ROWS / JSPLIT / 16 / CT)   // 8

__global__ __launch_bounds__(256, 2)
void gram_accum(const short* __restrict__ vph, const short* __restrict__ vpm,
                const float* __restrict__ out, float* __restrict__ res) {
  __shared__ __align__(16) short lh[2][CT * 1024];   // 2 x 16 KB
  __shared__ __align__(16) short lm[2][CT * 1024];   // 2 x 16 KB
  const int tid = threadIdx.x;
  const int wave = tid >> 6;
  const int lane = tid & 63;
  const int i0 = blockIdx.x * 128;                   // 8 i-tiles per block
  const int jbase = blockIdx.y * (B_ROWS / JSPLIT);  // 1024 j-rows

  // A-fragments: 8 i-tiles x 2 ksteps, hi+mid (128 VGPRs)
  short8 Ah[8][2], Am[8][2];
#pragma unroll
  for (int it = 0; it < 8; ++it) {
    const int It = (i0 >> 4) + it;
#pragma unroll
    for (int q = 0; q < 2; ++q) {
      Ah[it][q] = *(const short8*)(vph + (size_t)It * 1024 + q * 512 + lane * 8);
      Am[it][q] = *(const short8*)(vpm + (size_t)It * 1024 + q * 512 + lane * 8);
    }
  }

  auto stage = [&](int c, int bf) {
    const size_t base = ((size_t)(jbase >> 4) + c * CT) * 1024;
#pragma unroll
    for (int u = 0; u < 8; ++u) {
      const int item = wave * 8 + u;   // 0..31, wave-uniform
      const short* src;
      short* dst;
      if (item < 16) { src = vph + base + item * 512; dst = lh[bf] + item * 512; }
      else           { src = vpm + base + (item - 16) * 512; dst = lm[bf] + (item - 16) * 512; }
      __builtin_amdgcn_global_load_lds(
          (const __attribute__((address_space(1))) void*)(src + lane * 8),
          (__attribute__((address_space(3))) void*)dst, 16, 0, 0);
    }
  };

  stage(0, 0);
  for (int c = 0; c < NCHUNK; ++c) {
    __syncthreads();                       // chunk c staged; prior reads drained
    if (c + 1 < NCHUNK) stage(c + 1, (c + 1) & 1);
    const int bf = c & 1;
#pragma unroll
    for (int t = 0; t < 2; ++t) {
      const int jt = wave * 2 + t;
      const int j0 = jbase + (c * CT + jt) * 16;
      short8 Bh0 = *(const short8*)(lh[bf] + jt * 1024 + lane * 8);
      short8 Bh1 = *(const short8*)(lh[bf] + jt * 1024 + 512 + lane * 8);
      short8 Bm0 = *(const short8*)(lm[bf] + jt * 1024 + lane * 8);
      short8 Bm1 = *(const short8*)(lm[bf] + jt * 1024 + 512 + lane * 8);
      f32x4 g[8];
#pragma unroll
      for (int it = 0; it < 8; ++it) g[it] = (f32x4){0.f, 0.f, 0.f, 0.f};
      // straight-line MFMA region: 6 passes x 8 independent chains
#pragma unroll
      for (int it = 0; it < 8; ++it) g[it] = __builtin_amdgcn_mfma_f32_16x16x32_bf16(Ah[it][0], Bh0, g[it], 0, 0, 0);
#pragma unroll
      for (int it = 0; it < 8; ++it) g[it] = __builtin_amdgcn_mfma_f32_16x16x32_bf16(Ah[it][1], Bh1, g[it], 0, 0, 0);
#pragma unroll
      for (int it = 0; it < 8; ++it) g[it] = __builtin_amdgcn_mfma_f32_16x16x32_bf16(Ah[it][0], Bm0, g[it], 0, 0, 0);
#pragma unroll
      for (int it = 0; it < 8; ++it) g[it] = __builtin_amdgcn_mfma_f32_16x16x32_bf16(Am[it][0], Bh0, g[it], 0, 0, 0);
#pragma unroll
      for (int it = 0; it < 8; ++it) g[it] = __builtin_amdgcn_mfma_f32_16x16x32_bf16(Ah[it][1], Bm1, g[it], 0, 0, 0);
#pragma unroll
      for (int it = 0; it < 8; ++it) g[it] = __builtin_amdgcn_mfma_f32_16x16x32_bf16(Am[it][1], Bh1, g[it], 0, 0, 0);
      // threshold: one rare-taken branch per i-tile
#pragma unroll
      for (int it = 0; it < 8; ++it) {
        const float m01 = fmaxf(g[it][0] * g[it][0], g[it][1] * g[it][1]);
        const float m23 = fmaxf(g[it][2] * g[it][2], g[it][3] * g[it][3]);
        if (fmaxf(m01, m23) >= THRESH) {
          const int j = j0 + (lane & 15);
          const float* __restrict__ oj = out + (size_t)j * D_OUT;
#pragma unroll
          for (int r = 0; r < 4; ++r) {
            if (g[it][r] * g[it][r] >= THRESH) {
              const int i = i0 + it * 16 + (lane >> 4) * 4 + r;
              if (i != j) {
                float* __restrict__ ri = res + (size_t)i * D_OUT;
                for (int k = 0; k < D_OUT; ++k) atomicAdd(&ri[k], oj[k]);
              }
            }
          }
        }
      }
    }
  }
}

// ---------------- launch ----------------
#define MB (1024 * 1024)

extern "C" void kernel_launch(void* const* d_in, const int* in_sizes, int n_in,
                              void* d_out, int out_size, void* d_ws, size_t ws_size,
                              hipStream_t stream) {
  const float* x  = (const float*)d_in[0];
  const float* W1 = (const float*)d_in[1];
  const float* b1 = (const float*)d_in[2];
  const float* W2 = (const float*)d_in[3];
  const float* b2 = (const float*)d_in[4];
  const float* W3 = (const float*)d_in[5];
  const float* b3 = (const float*)d_in[6];
  float* res = (float*)d_out;

  char* ws = (char*)d_ws;
  // R1 (8 MB): xh/xm, later reused as h2h/h2m
  short* xh  = (short*)(ws + 0 * MB);
  short* xm  = (short*)(ws + 4 * MB);
  short* h2h = (short*)(ws + 0 * MB);
  short* h2m = (short*)(ws + 4 * MB);
  // R2 (16 MB): h1h/h1m, later reused for out/vph/vpm
  short* h1h = (short*)(ws + 8 * MB);
  short* h1m = (short*)(ws + 16 * MB);
  float* out = (float*)(ws + 8 * MB);
  short* vph = (short*)(ws + 11 * MB);
  short* vpm = (short*)(ws + 12 * MB);
  // R3: packed weights
  short* w1h = (short*)(ws + 24 * MB);
  short* w1m = (short*)(ws + 24 * MB + 256 * 1024);
  short* w2h = (short*)(ws + 24 * MB + 512 * 1024);
  short* w2m = (short*)(ws + 24 * MB + 768 * 1024);
  short* w3h = (short*)(ws + 25 * MB);
  short* w3m = (short*)(ws + 25 * MB + 32 * 1024);

  pack_inputs<<<1160, 256, 0, stream>>>(x, W1, W2, W3, xh, xm, w1h, w1m, w2h, w2m, w3h, w3m);
  // gemm1: [8192,256] @ W1^T -> tanh -> packed h1 (N=512)
  mfma_gemm<8, 4, 1><<<dim3(128, 4), 256, 0, stream>>>(
      xh, xm, w1h, w1m, b1, nullptr, h1h, h1m, H1_DIM, nullptr);
  // gemm2: [8192,512] @ W2^T -> tanh -> packed h2 (N=256)
  mfma_gemm<16, 2, 1><<<dim3(128, 4), 256, 0, stream>>>(
      h1h, h1m, w2h, w2m, b2, nullptr, h2h, h2m, H2_DIM, nullptr);
  // gemm3: [8192,256] @ W3^T + b -> fp32 out + normalized packed vph/vpm; zeros res
  mfma_gemm<8, 2, 2><<<dim3(128, 1), 256, 0, stream>>>(
      h2h, h2m, w3h, w3m, b3, out, vph, vpm, D_OUT, res);
  gram_accum<<<dim3(B_ROWS / 128, JSPLIT), 256, 0, stream>>>(vph, vpm, out, res);
}